// Round 7
// baseline (340.111 us; speedup 1.0000x reference)
//
#include <hip/hip_runtime.h>
#include <math.h>

#define BATCH 8
#define CH    64
#define NPTS  2048
#define KNN   20
#define OUTC  64

// Branchless sorted insert (ascending d[0..19], d[0] = 20th best).
// Precondition: iv > d[0].
__device__ __forceinline__ void ladder20(float (&d)[KNN], int (&id)[KNN], float iv, int ii) {
    bool ci = true;
    #pragma unroll
    for (int s = 0; s < KNN; ++s) {
        const bool  cn = (s < KNN-1) ? (iv > d[s+1]) : false;
        const float dn = (s < KNN-1) ? d[s+1] : 0.f;
        const int   gn = (s < KNN-1) ? id[s+1] : 0;
        d[s]  = cn ? dn : (ci ? iv : d[s]);
        id[s] = cn ? gn : (ci ? ii : id[s]);
        ci = cn;
    }
}

// prep: 512 blocks, 32-m tiles.
// y1t[b][m][o] = W1 . x[:,m] ; zt[b][n][o] = (W2-W1) . x[:,n] + bias ; xx = ||x_m||^2
__global__ __launch_bounds__(256) void edgeconv_prep(
    const float* __restrict__ x, const float* __restrict__ W,
    const float* __restrict__ bias,
    float* __restrict__ y1t, float* __restrict__ zt, float* __restrict__ xx)
{
    __shared__ __align__(16) float Wt1[64*65];   // [c][o] pad 65 (conflict-free)
    __shared__ __align__(16) float Wtd[64*65];
    __shared__ __align__(16) float xs [64*32];   // [c][m]
    const int tx  = threadIdx.x;
    const int bid = blockIdx.x;
    const int b   = bid >> 6;
    const int m0  = (bid & 63) << 5;
    const float* xb = x + (size_t)b * (CH * NPTS);

    {   // stage W transposed (pad 65)
        const int o  = tx >> 2;
        const int cb = (tx & 3) << 4;
        #pragma unroll
        for (int cc = 0; cc < 16; cc += 4) {
            const float4 w1 = *(const float4*)&W[o*128 + cb + cc];
            const float4 w2 = *(const float4*)&W[o*128 + 64 + cb + cc];
            const float a1[4] = {w1.x, w1.y, w1.z, w1.w};
            const float a2[4] = {w2.x, w2.y, w2.z, w2.w};
            #pragma unroll
            for (int e = 0; e < 4; ++e) {
                Wt1[(cb+cc+e)*65 + o] = a1[e];
                Wtd[(cb+cc+e)*65 + o] = a2[e] - a1[e];
            }
        }
    }
    {   // stage x tile [64c][32m]
        const int c0 = tx >> 2;
        const int j0 = (tx & 3) << 3;
        *(float4*)&xs[c0*32 + j0]     = *(const float4*)&xb[(size_t)c0*NPTS + m0 + j0];
        *(float4*)&xs[c0*32 + j0 + 4] = *(const float4*)&xb[(size_t)c0*NPTS + m0 + j0 + 4];
    }
    __syncthreads();

    if (tx < 32) {   // squared norms
        float s = 0.f;
        #pragma unroll
        for (int c = 0; c < 64; ++c) { const float v = xs[c*32 + tx]; s = fmaf(v, v, s); }
        xx[b*NPTS + m0 + tx] = s;
    }

    const int o  = tx & 63;   // lane = output channel (coalesced writes)
    const int mg = tx >> 6;   // wave -> 8-m chunk
    float y[8], z[8];
    const float bo = bias[o];
    #pragma unroll
    for (int i = 0; i < 8; ++i) { y[i] = 0.f; z[i] = bo; }
    #pragma unroll 8
    for (int c = 0; c < 64; ++c) {
        const float w1 = Wt1[c*65 + o];
        const float wd = Wtd[c*65 + o];
        float a[8];
        *(float4*)&a[0] = *(const float4*)&xs[c*32 + mg*8];
        *(float4*)&a[4] = *(const float4*)&xs[c*32 + mg*8 + 4];
        #pragma unroll
        for (int i = 0; i < 8; ++i) {
            y[i] = fmaf(w1, a[i], y[i]);
            z[i] = fmaf(wd, a[i], z[i]);
        }
    }
    #pragma unroll
    for (int i = 0; i < 8; ++i) {
        const int m = m0 + mg*8 + i;
        y1t[((size_t)b*NPTS + m)*64 + o] = y[i];
        zt [((size_t)b*NPTS + m)*64 + o] = z[i];
    }
}

// Main: fused kNN + gather + lrelu + max. 1024 blocks = (batch, 16-row tile),
// 4 blocks/CU (LDS 37120B). Thread (r=tx>>4, q=tx&15) owns row r, cols q*4..+3.
// Per c4-iter: 1 xnt b128 (16-way bcast) + 1 bufc b128 (16 disjoint quads) for
// 16 FMA. xx keys prefetched per-lane from global (no LDS). Final merge =
// register-shift tournament over the row's 16 lanes (no dynamic indexing).
__global__ __launch_bounds__(256) void edgeconv_main(
    const float* __restrict__ x,
    const float* __restrict__ y1t, const float* __restrict__ zt,
    const float* __restrict__ xx, float* __restrict__ out)
{
    __shared__ __align__(16) char pool[37120];
    float* xnt = (float*)pool;              // [16][68]   4352 (quad stride 17: conflict-free)
    float* xmb = (float*)(pool + 4352);     // [2][64][64] 32768 (double buffer)
    // phase-2 aliases (phase-1 data dead, barrier-separated):
    int*   ml     = (int*)pool;             // [16][20] 1280 merged knn idx
    float* outbuf = (float*)(pool + 1280);  // [16][68] 4352 epilogue staging

    const int tx  = threadIdx.x;
    const int bid = blockIdx.x;
    const int b   = bid >> 7;               // 128 row-tiles per batch
    const int n0  = (bid & 127) << 4;       // 16 rows
    const float* xb   = x  + (size_t)b * (CH * NPTS);
    const float* xxbg = xx + (size_t)b * NPTS;

    const int r = tx >> 4;          // my row (0..15)
    const int q = tx & 15;          // my col-quad: cols q*4..q*4+3

    {   // stage xnt [16][68]: lane (r, q*4) writes its 4 channel values (one-time)
        const int c4b = q << 2;
        #pragma unroll
        for (int i = 0; i < 4; ++i)
            xnt[r*68 + c4b + i] = xb[(size_t)(c4b + i)*NPTS + n0 + r];
    }
    {   // stage xm buffer 0 (m-tile 0)
        const int c = tx >> 4;
        const int j = (tx & 15) << 2;
        #pragma unroll
        for (int it = 0; it < 4; ++it)
            *(float4*)&xmb[(c + it*16)*64 + j] = *(const float4*)&xb[(size_t)(c + it*16)*NPTS + j];
    }

    float xq[4];
    *(float4*)&xq[0] = *(const float4*)&xxbg[q*4];   // tile-0 keys (global, L2)

    float d[KNN]; int id[KNN];
    #pragma unroll
    for (int k = 0; k < KNN; ++k) { d[k] = -INFINITY; id[k] = 0; }
    float thrR = -INFINITY;

    for (int t = 0; t < 32; ++t) {
        __syncthreads();            // buf[cur] ready; prior reads of buf[cur^1] done
        const int cur = t & 1;
        const float* bufc = xmb + cur*4096;
        float* bufn = xmb + (cur^1)*4096;

        // issue prefetch of next m-tile + next keys (latency hidden under Gram)
        float4 p0, p1, p2, p3, xqn;
        const int tn  = t + 1;
        const int jj  = (tx & 15) << 2;
        const int cc4 = tx >> 4;
        if (tn < 32) {
            const int mb2 = tn << 6;
            p0 = *(const float4*)&xb[(size_t)(cc4 +  0)*NPTS + mb2 + jj];
            p1 = *(const float4*)&xb[(size_t)(cc4 + 16)*NPTS + mb2 + jj];
            p2 = *(const float4*)&xb[(size_t)(cc4 + 32)*NPTS + mb2 + jj];
            p3 = *(const float4*)&xb[(size_t)(cc4 + 48)*NPTS + mb2 + jj];
            xqn = *(const float4*)&xxbg[mb2 + (q << 2)];
        }

        // Gram: acc[e] = dot(x_n[r], x_m[q*4+e])
        float acc[4];
        #pragma unroll
        for (int e = 0; e < 4; ++e) acc[e] = 0.f;
        #pragma unroll
        for (int c4 = 0; c4 < 64; c4 += 4) {
            float av[4];
            *(float4*)&av[0] = *(const float4*)&xnt[r*68 + c4];
            #pragma unroll
            for (int i = 0; i < 4; ++i) {
                float bv[4];
                *(float4*)&bv[0] = *(const float4*)&bufc[(c4+i)*64 + (q << 2)];
                #pragma unroll
                for (int e = 0; e < 4; ++e) acc[e] = fmaf(av[i], bv[e], acc[e]);
            }
        }

        // keys + candidate mask (strict > : lax.top_k tie semantics)
        float v[4];
        unsigned msk = 0u;
        #pragma unroll
        for (int e = 0; e < 4; ++e) {
            v[e] = fmaf(2.f, acc[e], -xq[e]);
            msk |= (v[e] > thrR) ? (1u << e) : 0u;
        }

        // drain: wave pays max-lane candidate count; values muxed from registers
        const int base = (t << 6) + (q << 2);
        while (__any(msk != 0u)) {
            const bool act = (msk != 0u);
            const int  e   = __ffs(msk) - 1;    // ascending e => ascending m (tie order)
            msk &= msk - 1u;
            const float t01 = (e & 1) ? v[1] : v[0];
            const float t23 = (e & 1) ? v[3] : v[2];
            const float vv  = (e & 2) ? t23 : t01;
            if (act && vv > d[0]) ladder20(d, id, vv, base + e);
        }

        // row-shared threshold: max over the row's 16 lanes of own 20th-best
        float tm = d[0];
        tm = fmaxf(tm, __shfl_xor(tm, 1));
        tm = fmaxf(tm, __shfl_xor(tm, 2));
        tm = fmaxf(tm, __shfl_xor(tm, 4));
        tm = fmaxf(tm, __shfl_xor(tm, 8));
        thrR = tm;

        if (tn < 32) {   // commit prefetched tile into the other buffer
            *(float4*)&bufn[(cc4 +  0)*64 + jj] = p0;
            *(float4*)&bufn[(cc4 + 16)*64 + jj] = p1;
            *(float4*)&bufn[(cc4 + 32)*64 + jj] = p2;
            *(float4*)&bufn[(cc4 + 48)*64 + jj] = p3;
            *(float4*)&xq[0] = xqn;
        }
    }
    __syncthreads();   // all Gram/xnt reads done; pool reusable

    // register-shift tournament: 20 rounds of 16-lane argmax; winner pops head.
    // Comparator (v desc, idx asc) == lax.top_k order; ids unique per lane.
    for (int k = 0; k < KNN; ++k) {
        float bv = d[KNN-1]; int bg = id[KNN-1];
        #pragma unroll
        for (int m = 1; m <= 8; m <<= 1) {
            const float ov = __shfl_xor(bv, m);
            const int   og = __shfl_xor(bg, m);
            if (ov > bv || (ov == bv && og < bg)) { bv = ov; bg = og; }
        }
        if (q == 0) ml[r*20 + k] = bg;
        if (d[KNN-1] == bv && id[KNN-1] == bg) {   // unique winner (first 20 picks real)
            #pragma unroll
            for (int s = KNN-1; s > 0; --s) { d[s] = d[s-1]; id[s] = id[s-1]; }
            d[0] = -INFINITY; id[0] = 0;
        }
    }
    __syncthreads();

    // epilogue: out[b,o,n] = max_k lrelu(y1t[m_k][o] + zt[n][o]); lane = o
    const int lane = tx & 63;
    const int w    = tx >> 6;
    const float* y1b = y1t + (size_t)b * NPTS * 64;
    const float* ztb = zt  + (size_t)b * NPTS * 64;

    #pragma unroll
    for (int rr = 0; rr < 4; ++rr) {
        const int rw = w*4 + rr;
        const int n  = n0 + rw;
        const float zv = ztb[(size_t)n*64 + lane];
        float acc = -INFINITY;
        #pragma unroll
        for (int k = 0; k < KNN; ++k) {
            const int m = ml[rw*20 + k];                 // LDS broadcast
            const float vv = y1b[(size_t)m*64 + lane];   // 256B row gather (L2)
            float h = vv + zv;
            h = fmaxf(h, 0.2f*h);                        // leaky relu, exact
            acc = fmaxf(acc, h);
        }
        outbuf[rw*68 + lane] = acc;
    }
    __syncthreads();
    float* ob = out + (size_t)b * OUTC * NPTS;
    #pragma unroll
    for (int qo = 0; qo < 4; ++qo) {
        const int o = w*16 + qo*4 + (lane >> 4);
        const int n = lane & 15;
        ob[(size_t)o*NPTS + n0 + n] = outbuf[n*68 + o];  // 64B segments, conflict-free
    }
}

extern "C" void kernel_launch(void* const* d_in, const int* in_sizes, int n_in,
                              void* d_out, int out_size, void* d_ws, size_t ws_size,
                              hipStream_t stream) {
    const float* x    = (const float*)d_in[0];   // (8,64,2048)
    const float* W    = (const float*)d_in[1];   // (64,128)
    const float* bias = (const float*)d_in[2];   // (64,)
    float* out = (float*)d_out;                  // (8,64,2048)

    // workspace: y1t (4MB) | zt (4MB) | xx (64KB)
    float* y1t = (float*)d_ws;
    float* zt  = y1t + (size_t)BATCH * NPTS * 64;
    float* xx  = zt  + (size_t)BATCH * NPTS * 64;

    edgeconv_prep<<<BATCH * (NPTS/32), 256, 0, stream>>>(x, W, bias, y1t, zt, xx);
    edgeconv_main<<<BATCH * (NPTS/16), 256, 0, stream>>>(x, y1t, zt, xx, out);
}